// Round 4
// baseline (243.754 us; speedup 1.0000x reference)
//
#include <hip/hip_runtime.h>
#include <hip/hip_fp16.h>
#include <math.h>

#define NDIM 1024
#define KDIM 64
#define BDIM 256
#define BKDIM 16384

typedef unsigned short u16;
typedef __attribute__((ext_vector_type(8))) short bf16x8;
typedef __attribute__((ext_vector_type(4))) float f32x4;

__device__ __forceinline__ float bf2f(u16 u) {
  union { unsigned u; float f; } x; x.u = ((unsigned)u) << 16; return x.f;
}
__device__ __forceinline__ u16 f2bf(float f) {
  union { float f; unsigned u; } x; x.f = f;
  unsigned u = x.u;
  u += 0x7fffu + ((u >> 16) & 1u);   // RNE
  return (u16)(u >> 16);
}
__device__ __forceinline__ u16 f2h(float f) { return __half_as_ushort(__float2half(f)); }
__device__ __forceinline__ float h2f(u16 u) { return __half2float(__ushort_as_half(u)); }

// ---------------- K1: row logsumexp of A_logits/T (fp32 in) ----------------
__global__ __launch_bounds__(256) void k_row_lse(const float* __restrict__ Alog,
                                                 float* __restrict__ r) {
  int m = blockIdx.x, t = threadIdx.x;
  float v[4], mx = -3.0e38f;
#pragma unroll
  for (int j = 0; j < 4; j++) {
    v[j] = Alog[m * NDIM + t + j * 256] * 5.0f;
    mx = fmaxf(mx, v[j]);
  }
  __shared__ float sred[256];
  sred[t] = mx; __syncthreads();
  for (int s = 128; s > 0; s >>= 1) { if (t < s) sred[t] = fmaxf(sred[t], sred[t + s]); __syncthreads(); }
  float bm = sred[0]; __syncthreads();
  float sm = 0.f;
#pragma unroll
  for (int j = 0; j < 4; j++) sm += expf(v[j] - bm);
  sred[t] = sm; __syncthreads();
  for (int s = 128; s > 0; s >>= 1) { if (t < s) sred[t] += sred[t + s]; __syncthreads(); }
  if (t == 0) r[m] = bm + logf(sred[0]);
}

// ------ K2: col logsumexp + write Dt[n][m] = A[m][n] - 1/N (bf16) ----------
__global__ __launch_bounds__(256) void k_col_dt(const float* __restrict__ Alog,
                                                const float* __restrict__ r,
                                                u16* __restrict__ Dt) {
  int n = blockIdx.x, t = threadIdx.x;
  float v[4], mx = -3.0e38f;
#pragma unroll
  for (int j = 0; j < 4; j++) {
    int m = t + j * 256;
    v[j] = Alog[m * NDIM + n] * 5.0f - r[m];
    mx = fmaxf(mx, v[j]);
  }
  __shared__ float sred[256];
  sred[t] = mx; __syncthreads();
  for (int s = 128; s > 0; s >>= 1) { if (t < s) sred[t] = fmaxf(sred[t], sred[t + s]); __syncthreads(); }
  float bm = sred[0]; __syncthreads();
  float sm = 0.f;
#pragma unroll
  for (int j = 0; j < 4; j++) sm += expf(v[j] - bm);
  sred[t] = sm; __syncthreads();
  for (int s = 128; s > 0; s >>= 1) { if (t < s) sred[t] += sred[t + s]; __syncthreads(); }
  float cn = bm + logf(sred[0]);
#pragma unroll
  for (int j = 0; j < 4; j++) {
    int m = t + j * 256;
    Dt[n * NDIM + m] = f2bf(expf(v[j] - cn) - 0.0009765625f);
  }
}

// ------ K3: W_logits = W1@WV (fp32), per-block sinkhorn, Wt[t][o][i] bf16 --
__global__ __launch_bounds__(256) void k_w(const float* __restrict__ W1,
                                           const float* __restrict__ WV,
                                           u16* __restrict__ Wt) {
  int tb = blockIdx.x, t = threadIdx.x;
  int d = t >> 2, q = t & 3;      // row d, col segment q*16..q*16+15
  float w1[8];
#pragma unroll
  for (int k = 0; k < 8; k++) w1[k] = W1[tb * 8 + k];
  float la[16];
#pragma unroll
  for (int j = 0; j < 16; j++) la[j] = 0.f;
#pragma unroll
  for (int k = 0; k < 8; k++) {
    float wk = w1[k];
    const float4* base = (const float4*)&WV[k * 4096 + d * 64 + q * 16];
#pragma unroll
    for (int v = 0; v < 4; v++) {
      float4 f = base[v];
      la[v * 4 + 0] += wk * f.x; la[v * 4 + 1] += wk * f.y;
      la[v * 4 + 2] += wk * f.z; la[v * 4 + 3] += wk * f.w;
    }
  }
  float mx = -3.0e38f;
#pragma unroll
  for (int j = 0; j < 16; j++) { la[j] *= 5.0f; mx = fmaxf(mx, la[j]); }
  float sm = 0.f;
#pragma unroll
  for (int j = 0; j < 16; j++) sm += expf(la[j] - mx);
  for (int off = 1; off < 4; off <<= 1) {   // combine 4 lanes of a row
    float mo = __shfl_xor(mx, off), so = __shfl_xor(sm, off);
    float mn = fmaxf(mx, mo);
    sm = sm * expf(mx - mn) + so * expf(mo - mn);
    mx = mn;
  }
  float rl = mx + logf(sm);
  __shared__ float sla[64 * 65];
#pragma unroll
  for (int j = 0; j < 16; j++) sla[d * 65 + q * 16 + j] = la[j] - rl;
  __syncthreads();
  int e = t >> 2, jj = t & 3;     // col e, row segment jj*16..jj*16+15
  float lb[16]; float m2 = -3.0e38f;
#pragma unroll
  for (int i = 0; i < 16; i++) { lb[i] = sla[(jj * 16 + i) * 65 + e]; m2 = fmaxf(m2, lb[i]); }
  float s2 = 0.f;
#pragma unroll
  for (int i = 0; i < 16; i++) s2 += expf(lb[i] - m2);
  for (int off = 1; off < 4; off <<= 1) {
    float mo = __shfl_xor(m2, off), so = __shfl_xor(s2, off);
    float mn = fmaxf(m2, mo);
    s2 = s2 * expf(m2 - mn) + so * expf(mo - mn);
    m2 = mn;
  }
  float cl = m2 + logf(s2);
#pragma unroll
  for (int i = 0; i < 16; i++)
    Wt[tb * 4096 + e * 64 + jj * 16 + i] = f2bf(expf(lb[i] - cl));  // Wt[t][o][i]=W[i][o]
}

// ------ K4: x_local = x@W per n; x fp32 split hi/lo bf16; xl fp16 [n][bk] --
__global__ __launch_bounds__(256) void k_gemm1(const float* __restrict__ x,
                                               const u16* __restrict__ Wt,
                                               u16* __restrict__ xl) {
  __shared__ __align__(16) u16 xhi[128 * 64];   // 16KB
  __shared__ __align__(16) u16 xlo[128 * 64];   // 16KB
  __shared__ __align__(16) u16 wsm[64 * 64];    // 8KB  [o][i]
  int n = blockIdx.x, t = threadIdx.x;
  {
    const uint4* src = (const uint4*)(Wt + n * 4096);
    uint4* dst = (uint4*)wsm;
    dst[t] = src[t];
    dst[t + 256] = src[t + 256];
  }
  int w = t >> 6, l = t & 63, q = l >> 4, lr = l & 15;
  int col4 = (t & 15) * 4;
  int rbase = t >> 4;
  for (int half = 0; half < 2; half++) {
    int b0 = half * 128;
    __syncthreads();   // protect previous half's LDS reads (and W staging, iter 0)
#pragma unroll
    for (int j = 0; j < 8; j++) {
      int rl2 = j * 16 + rbase;                 // 0..127
      float4 v = *(const float4*)&x[(size_t)(b0 + rl2) * 65536 + n * 64 + col4];
      ushort4 hi, lo;
      hi.x = f2bf(v.x); lo.x = f2bf(v.x - bf2f(hi.x));
      hi.y = f2bf(v.y); lo.y = f2bf(v.y - bf2f(hi.y));
      hi.z = f2bf(v.z); lo.z = f2bf(v.z - bf2f(hi.z));
      hi.w = f2bf(v.w); lo.w = f2bf(v.w - bf2f(hi.w));
      *(ushort4*)&xhi[rl2 * 64 + col4] = hi;
      *(ushort4*)&xlo[rl2 * 64 + col4] = lo;
    }
    __syncthreads();
    f32x4 acc[2][4] = {};
#pragma unroll
    for (int ks = 0; ks < 2; ks++) {
      bf16x8 ah[2], al[2], bfr[4];
#pragma unroll
      for (int mi = 0; mi < 2; mi++) {
        ah[mi] = *(const bf16x8*)&xhi[(w * 32 + mi * 16 + lr) * 64 + ks * 32 + q * 8];
        al[mi] = *(const bf16x8*)&xlo[(w * 32 + mi * 16 + lr) * 64 + ks * 32 + q * 8];
      }
#pragma unroll
      for (int ni = 0; ni < 4; ni++)
        bfr[ni] = *(const bf16x8*)&wsm[(ni * 16 + lr) * 64 + ks * 32 + q * 8];
#pragma unroll
      for (int mi = 0; mi < 2; mi++)
#pragma unroll
        for (int ni = 0; ni < 4; ni++) {
          acc[mi][ni] = __builtin_amdgcn_mfma_f32_16x16x32_bf16(ah[mi], bfr[ni], acc[mi][ni], 0, 0, 0);
          acc[mi][ni] = __builtin_amdgcn_mfma_f32_16x16x32_bf16(al[mi], bfr[ni], acc[mi][ni], 0, 0, 0);
        }
    }
#pragma unroll
    for (int mi = 0; mi < 2; mi++)
#pragma unroll
      for (int ni = 0; ni < 4; ni++) {
        int o = ni * 16 + lr;
#pragma unroll
        for (int reg = 0; reg < 4; reg++) {
          int b = b0 + w * 32 + mi * 16 + q * 4 + reg;
          xl[n * BKDIM + b * 64 + o] = f2h(acc[mi][ni][reg]);   // fp16 intermediate
        }
      }
  }
}

// ------ K5: LN over n per bk col (xl fp16) -> xln bf16 [bk][n]; sON fp32 ---
__global__ __launch_bounds__(256) void k_ln(const u16* __restrict__ xl,
                                            const float* __restrict__ g2,
                                            const float* __restrict__ b2,
                                            u16* __restrict__ xln,
                                            float* __restrict__ sON) {
  __shared__ float s_sum[32 * 64], s_ssq[32 * 64], s_wsx[32 * 64];
  __shared__ float s_gs[32], s_bs[32];
  __shared__ float s_mu[64], s_al[64];
  __shared__ __align__(16) u16 ldsT[64 * 136];
  int blk = blockIdx.x, t = threadIdx.x;
  int c0 = blk * 64;
  int rg = t >> 3, cs = t & 7;
  float sum[8], ssq[8], wsx[8];
#pragma unroll
  for (int j = 0; j < 8; j++) { sum[j] = 0.f; ssq[j] = 0.f; wsx[j] = 0.f; }
  float gs = 0.f, bs = 0.f;
  for (int it = 0; it < 32; it++) {
    int row = it * 32 + rg;
    bf16x8 v = *(const bf16x8*)&xl[row * BKDIM + c0 + cs * 8];
    float gm = g2[row], bt = b2[row];
    gs += gm; bs += bt;
#pragma unroll
    for (int j = 0; j < 8; j++) {
      float f = h2f((u16)v[j]);
      sum[j] += f; ssq[j] += f * f; wsx[j] += f * gm;
    }
  }
#pragma unroll
  for (int j = 0; j < 8; j++) {
    s_sum[rg * 64 + cs * 8 + j] = sum[j];
    s_ssq[rg * 64 + cs * 8 + j] = ssq[j];
    s_wsx[rg * 64 + cs * 8 + j] = wsx[j];
  }
  if (cs == 0) { s_gs[rg] = gs; s_bs[rg] = bs; }
  __syncthreads();
  if (t < 64) {
    float S = 0.f, Q = 0.f, Wx = 0.f, G = 0.f, Bt = 0.f;
    for (int k = 0; k < 32; k++) {
      S += s_sum[k * 64 + t]; Q += s_ssq[k * 64 + t]; Wx += s_wsx[k * 64 + t];
      G += s_gs[k]; Bt += s_bs[k];
    }
    float mu = S * (1.0f / 1024.0f);
    float var = Q * (1.0f / 1024.0f) - mu * mu;
    float al = rsqrtf(var + 1e-5f);
    s_mu[t] = mu; s_al[t] = al;
    sON[c0 + t] = (al * (Wx - mu * G) + Bt) * (1.0f / 1024.0f);
  }
  __syncthreads();
  for (int ch = 0; ch < 8; ch++) {
#pragma unroll
    for (int si = 0; si < 4; si++) {
      int rl = si * 32 + rg;
      int row = ch * 128 + rl;
      bf16x8 v = *(const bf16x8*)&xl[row * BKDIM + c0 + cs * 8];
      float gm = g2[row], bt = b2[row];
#pragma unroll
      for (int j = 0; j < 8; j++) {
        int col = cs * 8 + j;
        float f = (h2f((u16)v[j]) - s_mu[col]) * s_al[col] * gm + bt;
        ldsT[col * 136 + rl] = f2bf(f);
      }
    }
    __syncthreads();
    int c2 = t >> 2, sg = t & 3;
    const u16* src = &ldsT[c2 * 136 + sg * 32];
    u16* dst = &xln[(c0 + c2) * NDIM + ch * 128 + sg * 32];
#pragma unroll
    for (int k = 0; k < 4; k++)
      *(bf16x8*)&dst[k * 8] = *(const bf16x8*)&src[k * 8];
    __syncthreads();
  }
}

// ------ K6: C^T[n2][bk] = sum_m Dt[n2][m]*xln[bk][m]; out = C^T + s/N (f32)
__global__ __launch_bounds__(256) void k_gemm2(const u16* __restrict__ Dt,
                                               const u16* __restrict__ xln,
                                               const float* __restrict__ sON,
                                               float* __restrict__ out) {
  __shared__ __align__(16) u16 lA[128 * 64];  // [n2_local][m]
  __shared__ __align__(16) u16 lB[128 * 64];  // [bk_local][m]
  int bkt = blockIdx.x, n2t = blockIdx.y;
  int t = threadIdx.x, w = t >> 6, l = t & 63;
  int q = l >> 4, lr = l & 15;
  f32x4 acc[4][4] = {};
  for (int kt = 0; kt < 16; kt++) {
#pragma unroll
    for (int j = 0; j < 4; j++) {
      int ci = j * 4 + w;
      int row = ci * 8 + (l >> 3);
      *(uint4*)((char*)lA + ci * 1024 + l * 16) =
          *(const uint4*)((const char*)(Dt + (n2t * 128 + row) * NDIM + kt * 64) + (l & 7) * 16);
      *(uint4*)((char*)lB + ci * 1024 + l * 16) =
          *(const uint4*)((const char*)(xln + (bkt * 128 + row) * NDIM + kt * 64) + (l & 7) * 16);
    }
    __syncthreads();
#pragma unroll
    for (int ks = 0; ks < 2; ks++) {
      bf16x8 af[4], bfr[4];
#pragma unroll
      for (int mi = 0; mi < 4; mi++)
        af[mi] = *(const bf16x8*)&lA[((w >> 1) * 64 + mi * 16 + lr) * 64 + ks * 32 + q * 8];
#pragma unroll
      for (int ni = 0; ni < 4; ni++)
        bfr[ni] = *(const bf16x8*)&lB[((w & 1) * 64 + ni * 16 + lr) * 64 + ks * 32 + q * 8];
#pragma unroll
      for (int mi = 0; mi < 4; mi++)
#pragma unroll
        for (int ni = 0; ni < 4; ni++)
          acc[mi][ni] = __builtin_amdgcn_mfma_f32_16x16x32_bf16(af[mi], bfr[ni], acc[mi][ni], 0, 0, 0);
    }
    __syncthreads();
  }
#pragma unroll
  for (int ni = 0; ni < 4; ni++) {
    int bk = bkt * 128 + (w & 1) * 64 + ni * 16 + lr;
    float sN = sON[bk];
    int b = bk >> 6, o = bk & 63;
#pragma unroll
    for (int mi = 0; mi < 4; mi++)
#pragma unroll
      for (int reg = 0; reg < 4; reg++) {
        int n2 = n2t * 128 + (w >> 1) * 64 + mi * 16 + q * 4 + reg;
        out[(size_t)b * 65536 + n2 * 64 + o] = acc[mi][ni][reg] + sN;   // fp32 store
      }
  }
}

extern "C" void kernel_launch(void* const* d_in, const int* in_sizes, int n_in,
                              void* d_out, int out_size, void* d_ws, size_t ws_size,
                              hipStream_t stream) {
  const float* x    = (const float*)d_in[0];
  const float* Alog = (const float*)d_in[1];
  const float* W1   = (const float*)d_in[2];
  const float* WV   = (const float*)d_in[3];
  const float* g2   = (const float*)d_in[4];
  const float* b2   = (const float*)d_in[5];
  float* out = (float*)d_out;                       // fp32 output, 64 MiB
  char* ws = (char*)d_ws;

  u16*   xln = (u16*)(ws);                          // 32 MiB: [16384][1024] bf16
  u16*   Wt  = (u16*)(ws + 33554432ull);            //  8 MiB: [1024][4096] bf16
  u16*   Dt  = (u16*)(ws + 41943040ull);            //  2 MiB: [1024][1024] bf16
  float* r   = (float*)(ws + 44040192ull);          //  4 KiB
  float* sON = (float*)(ws + 44044288ull);          // 64 KiB
  // fp16 xl scratch lives in the UPPER half of the 64 MiB fp32 out buffer;
  // dead before K6 overwrites all of d_out (stream-ordered).
  u16*   xl  = (u16*)((char*)d_out + 33554432ull);  // 32 MiB: [1024][16384] fp16

  k_row_lse<<<dim3(1024), dim3(256), 0, stream>>>(Alog, r);
  k_col_dt<<<dim3(1024), dim3(256), 0, stream>>>(Alog, r, Dt);
  k_w<<<dim3(1024), dim3(256), 0, stream>>>(W1, WV, Wt);
  k_gemm1<<<dim3(1024), dim3(256), 0, stream>>>(x, Wt, xl);
  k_ln<<<dim3(256), dim3(256), 0, stream>>>(xl, g2, b2, xln, sON);
  k_gemm2<<<dim3(128, 8), dim3(256), 0, stream>>>(Dt, xln, sON, out);
}

// Round 5
// 231.787 us; speedup vs baseline: 1.0516x; 1.0516x over previous
//
#include <hip/hip_runtime.h>
#include <hip/hip_fp16.h>
#include <math.h>

#define NDIM 1024
#define KDIM 64
#define BDIM 256
#define BKDIM 16384

typedef unsigned short u16;
typedef __attribute__((ext_vector_type(8))) short bf16x8;
typedef __attribute__((ext_vector_type(4))) float f32x4;

__device__ __forceinline__ float bf2f(u16 u) {
  union { unsigned u; float f; } x; x.u = ((unsigned)u) << 16; return x.f;
}
__device__ __forceinline__ u16 f2bf(float f) {
  union { float f; unsigned u; } x; x.f = f;
  unsigned u = x.u;
  u += 0x7fffu + ((u >> 16) & 1u);   // RNE
  return (u16)(u >> 16);
}
__device__ __forceinline__ u16 f2h(float f) { return __half_as_ushort(__float2half(f)); }
__device__ __forceinline__ float h2f(u16 u) { return __half2float(__ushort_as_half(u)); }

// async 16B global->LDS (DMA, no VGPR roundtrip). LDS side must be
// wave-uniform base + lane*16; global side is per-lane (free gather).
__device__ __forceinline__ void async16(const u16* g, u16* s) {
  __builtin_amdgcn_global_load_lds(
      (const __attribute__((address_space(1))) unsigned int*)g,
      (__attribute__((address_space(3))) unsigned int*)s,
      16, 0, 0);
}

// ---------------- K1: row logsumexp of A_logits/T (fp32 in) ----------------
__global__ __launch_bounds__(256) void k_row_lse(const float* __restrict__ Alog,
                                                 float* __restrict__ r) {
  int m = blockIdx.x, t = threadIdx.x;
  float v[4], mx = -3.0e38f;
#pragma unroll
  for (int j = 0; j < 4; j++) {
    v[j] = Alog[m * NDIM + t + j * 256] * 5.0f;
    mx = fmaxf(mx, v[j]);
  }
  __shared__ float sred[256];
  sred[t] = mx; __syncthreads();
  for (int s = 128; s > 0; s >>= 1) { if (t < s) sred[t] = fmaxf(sred[t], sred[t + s]); __syncthreads(); }
  float bm = sred[0]; __syncthreads();
  float sm = 0.f;
#pragma unroll
  for (int j = 0; j < 4; j++) sm += expf(v[j] - bm);
  sred[t] = sm; __syncthreads();
  for (int s = 128; s > 0; s >>= 1) { if (t < s) sred[t] += sred[t + s]; __syncthreads(); }
  if (t == 0) r[m] = bm + logf(sred[0]);
}

// ------ K2: col logsumexp + write Dt[n][m] = A[m][n] - 1/N (bf16) ----------
__global__ __launch_bounds__(256) void k_col_dt(const float* __restrict__ Alog,
                                                const float* __restrict__ r,
                                                u16* __restrict__ Dt) {
  int n = blockIdx.x, t = threadIdx.x;
  float v[4], mx = -3.0e38f;
#pragma unroll
  for (int j = 0; j < 4; j++) {
    int m = t + j * 256;
    v[j] = Alog[m * NDIM + n] * 5.0f - r[m];
    mx = fmaxf(mx, v[j]);
  }
  __shared__ float sred[256];
  sred[t] = mx; __syncthreads();
  for (int s = 128; s > 0; s >>= 1) { if (t < s) sred[t] = fmaxf(sred[t], sred[t + s]); __syncthreads(); }
  float bm = sred[0]; __syncthreads();
  float sm = 0.f;
#pragma unroll
  for (int j = 0; j < 4; j++) sm += expf(v[j] - bm);
  sred[t] = sm; __syncthreads();
  for (int s = 128; s > 0; s >>= 1) { if (t < s) sred[t] += sred[t + s]; __syncthreads(); }
  float cn = bm + logf(sred[0]);
#pragma unroll
  for (int j = 0; j < 4; j++) {
    int m = t + j * 256;
    Dt[n * NDIM + m] = f2bf(expf(v[j] - cn) - 0.0009765625f);
  }
}

// ------ K3: W_logits = W1@WV (fp32), per-block sinkhorn, Wt[t][o][i] bf16 --
__global__ __launch_bounds__(256) void k_w(const float* __restrict__ W1,
                                           const float* __restrict__ WV,
                                           u16* __restrict__ Wt) {
  int tb = blockIdx.x, t = threadIdx.x;
  int d = t >> 2, q = t & 3;      // row d, col segment q*16..q*16+15
  float w1[8];
#pragma unroll
  for (int k = 0; k < 8; k++) w1[k] = W1[tb * 8 + k];
  float la[16];
#pragma unroll
  for (int j = 0; j < 16; j++) la[j] = 0.f;
#pragma unroll
  for (int k = 0; k < 8; k++) {
    float wk = w1[k];
    const float4* base = (const float4*)&WV[k * 4096 + d * 64 + q * 16];
#pragma unroll
    for (int v = 0; v < 4; v++) {
      float4 f = base[v];
      la[v * 4 + 0] += wk * f.x; la[v * 4 + 1] += wk * f.y;
      la[v * 4 + 2] += wk * f.z; la[v * 4 + 3] += wk * f.w;
    }
  }
  float mx = -3.0e38f;
#pragma unroll
  for (int j = 0; j < 16; j++) { la[j] *= 5.0f; mx = fmaxf(mx, la[j]); }
  float sm = 0.f;
#pragma unroll
  for (int j = 0; j < 16; j++) sm += expf(la[j] - mx);
  for (int off = 1; off < 4; off <<= 1) {   // combine 4 lanes of a row
    float mo = __shfl_xor(mx, off), so = __shfl_xor(sm, off);
    float mn = fmaxf(mx, mo);
    sm = sm * expf(mx - mn) + so * expf(mo - mn);
    mx = mn;
  }
  float rl = mx + logf(sm);
  __shared__ float sla[64 * 65];
#pragma unroll
  for (int j = 0; j < 16; j++) sla[d * 65 + q * 16 + j] = la[j] - rl;
  __syncthreads();
  int e = t >> 2, jj = t & 3;     // col e, row segment jj*16..jj*16+15
  float lb[16]; float m2 = -3.0e38f;
#pragma unroll
  for (int i = 0; i < 16; i++) { lb[i] = sla[(jj * 16 + i) * 65 + e]; m2 = fmaxf(m2, lb[i]); }
  float s2 = 0.f;
#pragma unroll
  for (int i = 0; i < 16; i++) s2 += expf(lb[i] - m2);
  for (int off = 1; off < 4; off <<= 1) {
    float mo = __shfl_xor(m2, off), so = __shfl_xor(s2, off);
    float mn = fmaxf(m2, mo);
    s2 = s2 * expf(m2 - mn) + so * expf(mo - mn);
    m2 = mn;
  }
  float cl = m2 + logf(s2);
#pragma unroll
  for (int i = 0; i < 16; i++)
    Wt[tb * 4096 + e * 64 + jj * 16 + i] = f2bf(expf(lb[i] - cl));  // Wt[t][o][i]=W[i][o]
}

// ------ K4: x_local = x@W per n; x fp32 split hi/lo bf16; xl fp16 [n][bk] --
__global__ __launch_bounds__(256) void k_gemm1(const float* __restrict__ x,
                                               const u16* __restrict__ Wt,
                                               u16* __restrict__ xl) {
  __shared__ __align__(16) u16 xhi[128 * 64];   // 16KB
  __shared__ __align__(16) u16 xlo[128 * 64];   // 16KB
  __shared__ __align__(16) u16 wsm[64 * 64];    // 8KB  [o][i]
  int n = blockIdx.x, t = threadIdx.x;
  {
    const uint4* src = (const uint4*)(Wt + n * 4096);
    uint4* dst = (uint4*)wsm;
    dst[t] = src[t];
    dst[t + 256] = src[t + 256];
  }
  int w = t >> 6, l = t & 63, q = l >> 4, lr = l & 15;
  int col4 = (t & 15) * 4;
  int rbase = t >> 4;
  for (int half = 0; half < 2; half++) {
    int b0 = half * 128;
    __syncthreads();   // protect previous half's LDS reads (and W staging, iter 0)
#pragma unroll
    for (int j = 0; j < 8; j++) {
      int rl2 = j * 16 + rbase;                 // 0..127
      float4 v = *(const float4*)&x[(size_t)(b0 + rl2) * 65536 + n * 64 + col4];
      ushort4 hi, lo;
      hi.x = f2bf(v.x); lo.x = f2bf(v.x - bf2f(hi.x));
      hi.y = f2bf(v.y); lo.y = f2bf(v.y - bf2f(hi.y));
      hi.z = f2bf(v.z); lo.z = f2bf(v.z - bf2f(hi.z));
      hi.w = f2bf(v.w); lo.w = f2bf(v.w - bf2f(hi.w));
      *(ushort4*)&xhi[rl2 * 64 + col4] = hi;
      *(ushort4*)&xlo[rl2 * 64 + col4] = lo;
    }
    __syncthreads();
    f32x4 acc[2][4] = {};
#pragma unroll
    for (int ks = 0; ks < 2; ks++) {
      bf16x8 ah[2], al[2], bfr[4];
#pragma unroll
      for (int mi = 0; mi < 2; mi++) {
        ah[mi] = *(const bf16x8*)&xhi[(w * 32 + mi * 16 + lr) * 64 + ks * 32 + q * 8];
        al[mi] = *(const bf16x8*)&xlo[(w * 32 + mi * 16 + lr) * 64 + ks * 32 + q * 8];
      }
#pragma unroll
      for (int ni = 0; ni < 4; ni++)
        bfr[ni] = *(const bf16x8*)&wsm[(ni * 16 + lr) * 64 + ks * 32 + q * 8];
#pragma unroll
      for (int mi = 0; mi < 2; mi++)
#pragma unroll
        for (int ni = 0; ni < 4; ni++) {
          acc[mi][ni] = __builtin_amdgcn_mfma_f32_16x16x32_bf16(ah[mi], bfr[ni], acc[mi][ni], 0, 0, 0);
          acc[mi][ni] = __builtin_amdgcn_mfma_f32_16x16x32_bf16(al[mi], bfr[ni], acc[mi][ni], 0, 0, 0);
        }
    }
#pragma unroll
    for (int mi = 0; mi < 2; mi++)
#pragma unroll
      for (int ni = 0; ni < 4; ni++) {
        int o = ni * 16 + lr;
#pragma unroll
        for (int reg = 0; reg < 4; reg++) {
          int b = b0 + w * 32 + mi * 16 + q * 4 + reg;
          xl[n * BKDIM + b * 64 + o] = f2h(acc[mi][ni][reg]);   // fp16 intermediate
        }
      }
  }
}

// ------ K5: LN over n per bk col (xl fp16) -> xln bf16 [bk][n]; sON fp32 ---
__global__ __launch_bounds__(256) void k_ln(const u16* __restrict__ xl,
                                            const float* __restrict__ g2,
                                            const float* __restrict__ b2,
                                            u16* __restrict__ xln,
                                            float* __restrict__ sON) {
  __shared__ float s_sum[32 * 64], s_ssq[32 * 64], s_wsx[32 * 64];
  __shared__ float s_gs[32], s_bs[32];
  __shared__ float s_mu[64], s_al[64];
  __shared__ __align__(16) u16 ldsT[64 * 136];
  int blk = blockIdx.x, t = threadIdx.x;
  int c0 = blk * 64;
  int rg = t >> 3, cs = t & 7;
  float sum[8], ssq[8], wsx[8];
#pragma unroll
  for (int j = 0; j < 8; j++) { sum[j] = 0.f; ssq[j] = 0.f; wsx[j] = 0.f; }
  float gs = 0.f, bs = 0.f;
  for (int it = 0; it < 32; it++) {
    int row = it * 32 + rg;
    bf16x8 v = *(const bf16x8*)&xl[row * BKDIM + c0 + cs * 8];
    float gm = g2[row], bt = b2[row];
    gs += gm; bs += bt;
#pragma unroll
    for (int j = 0; j < 8; j++) {
      float f = h2f((u16)v[j]);
      sum[j] += f; ssq[j] += f * f; wsx[j] += f * gm;
    }
  }
#pragma unroll
  for (int j = 0; j < 8; j++) {
    s_sum[rg * 64 + cs * 8 + j] = sum[j];
    s_ssq[rg * 64 + cs * 8 + j] = ssq[j];
    s_wsx[rg * 64 + cs * 8 + j] = wsx[j];
  }
  if (cs == 0) { s_gs[rg] = gs; s_bs[rg] = bs; }
  __syncthreads();
  if (t < 64) {
    float S = 0.f, Q = 0.f, Wx = 0.f, G = 0.f, Bt = 0.f;
    for (int k = 0; k < 32; k++) {
      S += s_sum[k * 64 + t]; Q += s_ssq[k * 64 + t]; Wx += s_wsx[k * 64 + t];
      G += s_gs[k]; Bt += s_bs[k];
    }
    float mu = S * (1.0f / 1024.0f);
    float var = Q * (1.0f / 1024.0f) - mu * mu;
    float al = rsqrtf(var + 1e-5f);
    s_mu[t] = mu; s_al[t] = al;
    sON[c0 + t] = (al * (Wx - mu * G) + Bt) * (1.0f / 1024.0f);
  }
  __syncthreads();
  for (int ch = 0; ch < 8; ch++) {
#pragma unroll
    for (int si = 0; si < 4; si++) {
      int rl = si * 32 + rg;
      int row = ch * 128 + rl;
      bf16x8 v = *(const bf16x8*)&xl[row * BKDIM + c0 + cs * 8];
      float gm = g2[row], bt = b2[row];
#pragma unroll
      for (int j = 0; j < 8; j++) {
        int col = cs * 8 + j;
        float f = (h2f((u16)v[j]) - s_mu[col]) * s_al[col] * gm + bt;
        ldsT[col * 136 + rl] = f2bf(f);
      }
    }
    __syncthreads();
    int c2 = t >> 2, sg = t & 3;
    const u16* src = &ldsT[c2 * 136 + sg * 32];
    u16* dst = &xln[(c0 + c2) * NDIM + ch * 128 + sg * 32];
#pragma unroll
    for (int k = 0; k < 4; k++)
      *(bf16x8*)&dst[k * 8] = *(const bf16x8*)&src[k * 8];
    __syncthreads();
  }
}

// ------ K6: C^T[n2][bk] = sum_m Dt[n2][m]*xln[bk][m]; out = C^T + s/N (f32)
// v2: async global_load_lds staging + XOR chunk swizzle (conflict-free reads).
// LDS tile row r (128B = 8 chunks of 16B): logical chunk c stored at physical
// chunk c^(r&7). Staging realizes the swizzle by permuting the per-lane
// GLOBAL source chunk (LDS side stays wave-uniform base + lane*16).
__global__ __launch_bounds__(256) void k_gemm2(const u16* __restrict__ Dt,
                                               const u16* __restrict__ xln,
                                               const float* __restrict__ sON,
                                               float* __restrict__ out) {
  __shared__ __align__(16) u16 lA[128 * 64];  // [n2_local][m], swizzled
  __shared__ __align__(16) u16 lB[128 * 64];  // [bk_local][m], swizzled
  int bkt = blockIdx.x, n2t = blockIdx.y;
  int t = threadIdx.x, w = t >> 6, l = t & 63;
  int q = l >> 4, lr = l & 15;
  int rr = l >> 3;                 // row within 8-row group (0..7)
  int cc = (l & 7) ^ rr;           // logical chunk this lane fetches
  const u16* gA = Dt  + (size_t)(n2t * 128) * NDIM + cc * 8;
  const u16* gB = xln + (size_t)(bkt * 128) * NDIM + cc * 8;
  f32x4 acc[4][4] = {};
  for (int kt = 0; kt < 16; kt++) {
#pragma unroll
    for (int j = 0; j < 4; j++) {
      int ci = j * 4 + w;
      int row = ci * 8 + rr;
      async16(gA + (size_t)row * NDIM + kt * 64, &lA[ci * 512 + l * 8]);
      async16(gB + (size_t)row * NDIM + kt * 64, &lB[ci * 512 + l * 8]);
    }
    __syncthreads();   // drains vmcnt (global_load_lds) per barrier semantics
#pragma unroll
    for (int ks = 0; ks < 2; ks++) {
      int pc = ((ks * 4 + q) ^ (lr & 7)) * 8;   // physical chunk offset (halves)
      bf16x8 af[4], bfr[4];
#pragma unroll
      for (int mi = 0; mi < 4; mi++)
        af[mi] = *(const bf16x8*)&lA[((w >> 1) * 64 + mi * 16 + lr) * 64 + pc];
#pragma unroll
      for (int ni = 0; ni < 4; ni++)
        bfr[ni] = *(const bf16x8*)&lB[((w & 1) * 64 + ni * 16 + lr) * 64 + pc];
#pragma unroll
      for (int mi = 0; mi < 4; mi++)
#pragma unroll
        for (int ni = 0; ni < 4; ni++)
          acc[mi][ni] = __builtin_amdgcn_mfma_f32_16x16x32_bf16(af[mi], bfr[ni], acc[mi][ni], 0, 0, 0);
    }
    __syncthreads();   // tile consumed before next iter's DMA overwrites
  }
#pragma unroll
  for (int ni = 0; ni < 4; ni++) {
    int bk = bkt * 128 + (w & 1) * 64 + ni * 16 + lr;
    float sN = sON[bk];
    int b = bk >> 6, o = bk & 63;
#pragma unroll
    for (int mi = 0; mi < 4; mi++)
#pragma unroll
      for (int reg = 0; reg < 4; reg++) {
        int n2 = n2t * 128 + (w >> 1) * 64 + mi * 16 + q * 4 + reg;
        out[(size_t)b * 65536 + n2 * 64 + o] = acc[mi][ni][reg] + sN;   // fp32 store
      }
  }
}

extern "C" void kernel_launch(void* const* d_in, const int* in_sizes, int n_in,
                              void* d_out, int out_size, void* d_ws, size_t ws_size,
                              hipStream_t stream) {
  const float* x    = (const float*)d_in[0];
  const float* Alog = (const float*)d_in[1];
  const float* W1   = (const float*)d_in[2];
  const float* WV   = (const float*)d_in[3];
  const float* g2   = (const float*)d_in[4];
  const float* b2   = (const float*)d_in[5];
  float* out = (float*)d_out;                       // fp32 output, 64 MiB
  char* ws = (char*)d_ws;

  u16*   xln = (u16*)(ws);                          // 32 MiB: [16384][1024] bf16
  u16*   Wt  = (u16*)(ws + 33554432ull);            //  8 MiB: [1024][4096] bf16
  u16*   Dt  = (u16*)(ws + 41943040ull);            //  2 MiB: [1024][1024] bf16
  float* r   = (float*)(ws + 44040192ull);          //  4 KiB
  float* sON = (float*)(ws + 44044288ull);          // 64 KiB
  // fp16 xl scratch lives in the UPPER half of the 64 MiB fp32 out buffer;
  // dead before K6 overwrites all of d_out (stream-ordered).
  u16*   xl  = (u16*)((char*)d_out + 33554432ull);  // 32 MiB: [1024][16384] fp16

  k_row_lse<<<dim3(1024), dim3(256), 0, stream>>>(Alog, r);
  k_col_dt<<<dim3(1024), dim3(256), 0, stream>>>(Alog, r, Dt);
  k_w<<<dim3(1024), dim3(256), 0, stream>>>(W1, WV, Wt);
  k_gemm1<<<dim3(1024), dim3(256), 0, stream>>>(x, Wt, xl);
  k_ln<<<dim3(256), dim3(256), 0, stream>>>(xl, g2, b2, xln, sON);
  k_gemm2<<<dim3(128, 8), dim3(256), 0, stream>>>(Dt, xln, sON, out);
}

// Round 6
// 229.880 us; speedup vs baseline: 1.0604x; 1.0083x over previous
//
#include <hip/hip_runtime.h>
#include <hip/hip_fp16.h>
#include <math.h>

#define NDIM 1024
#define KDIM 64
#define BDIM 256
#define BKDIM 16384

typedef unsigned short u16;
typedef __attribute__((ext_vector_type(8))) short bf16x8;
typedef __attribute__((ext_vector_type(4))) float f32x4;

__device__ __forceinline__ float bf2f(u16 u) {
  union { unsigned u; float f; } x; x.u = ((unsigned)u) << 16; return x.f;
}
__device__ __forceinline__ u16 f2bf(float f) {
  union { float f; unsigned u; } x; x.f = f;
  unsigned u = x.u;
  u += 0x7fffu + ((u >> 16) & 1u);   // RNE
  return (u16)(u >> 16);
}
__device__ __forceinline__ u16 f2h(float f) { return __half_as_ushort(__float2half(f)); }
__device__ __forceinline__ float h2f(u16 u) { return __half2float(__ushort_as_half(u)); }

// async 16B global->LDS (DMA, no VGPR roundtrip). LDS side must be
// wave-uniform base + lane*16; global side is per-lane (free gather).
__device__ __forceinline__ void async16(const u16* g, u16* s) {
  __builtin_amdgcn_global_load_lds(
      (const __attribute__((address_space(1))) unsigned int*)g,
      (__attribute__((address_space(3))) unsigned int*)s,
      16, 0, 0);
}

// ---------------- K1: row logsumexp of A_logits/T (fp32 in) ----------------
__global__ __launch_bounds__(256) void k_row_lse(const float* __restrict__ Alog,
                                                 float* __restrict__ r) {
  int m = blockIdx.x, t = threadIdx.x;
  float v[4], mx = -3.0e38f;
#pragma unroll
  for (int j = 0; j < 4; j++) {
    v[j] = Alog[m * NDIM + t + j * 256] * 5.0f;
    mx = fmaxf(mx, v[j]);
  }
  __shared__ float sred[256];
  sred[t] = mx; __syncthreads();
  for (int s = 128; s > 0; s >>= 1) { if (t < s) sred[t] = fmaxf(sred[t], sred[t + s]); __syncthreads(); }
  float bm = sred[0]; __syncthreads();
  float sm = 0.f;
#pragma unroll
  for (int j = 0; j < 4; j++) sm += __expf(v[j] - bm);
  sred[t] = sm; __syncthreads();
  for (int s = 128; s > 0; s >>= 1) { if (t < s) sred[t] += sred[t + s]; __syncthreads(); }
  if (t == 0) r[m] = bm + __logf(sred[0]);
}

// ------ K2: col logsumexp + write Dt[n][m] = A[m][n] - 1/N (bf16) ----------
__global__ __launch_bounds__(256) void k_col_dt(const float* __restrict__ Alog,
                                                const float* __restrict__ r,
                                                u16* __restrict__ Dt) {
  int n = blockIdx.x, t = threadIdx.x;
  float v[4], mx = -3.0e38f;
#pragma unroll
  for (int j = 0; j < 4; j++) {
    int m = t + j * 256;
    v[j] = Alog[m * NDIM + n] * 5.0f - r[m];
    mx = fmaxf(mx, v[j]);
  }
  __shared__ float sred[256];
  sred[t] = mx; __syncthreads();
  for (int s = 128; s > 0; s >>= 1) { if (t < s) sred[t] = fmaxf(sred[t], sred[t + s]); __syncthreads(); }
  float bm = sred[0]; __syncthreads();
  float sm = 0.f;
#pragma unroll
  for (int j = 0; j < 4; j++) sm += __expf(v[j] - bm);
  sred[t] = sm; __syncthreads();
  for (int s = 128; s > 0; s >>= 1) { if (t < s) sred[t] += sred[t + s]; __syncthreads(); }
  float cn = bm + __logf(sred[0]);
#pragma unroll
  for (int j = 0; j < 4; j++) {
    int m = t + j * 256;
    Dt[n * NDIM + m] = f2bf(__expf(v[j] - cn) - 0.0009765625f);
  }
}

// ------ K3: W_logits = W1@WV (fp32), per-block sinkhorn, Wt[t][o][i] bf16 --
__global__ __launch_bounds__(256) void k_w(const float* __restrict__ W1,
                                           const float* __restrict__ WV,
                                           u16* __restrict__ Wt) {
  int tb = blockIdx.x, t = threadIdx.x;
  int d = t >> 2, q = t & 3;      // row d, col segment q*16..q*16+15
  float w1[8];
#pragma unroll
  for (int k = 0; k < 8; k++) w1[k] = W1[tb * 8 + k];
  float la[16];
#pragma unroll
  for (int j = 0; j < 16; j++) la[j] = 0.f;
#pragma unroll
  for (int k = 0; k < 8; k++) {
    float wk = w1[k];
    const float4* base = (const float4*)&WV[k * 4096 + d * 64 + q * 16];
#pragma unroll
    for (int v = 0; v < 4; v++) {
      float4 f = base[v];
      la[v * 4 + 0] += wk * f.x; la[v * 4 + 1] += wk * f.y;
      la[v * 4 + 2] += wk * f.z; la[v * 4 + 3] += wk * f.w;
    }
  }
  float mx = -3.0e38f;
#pragma unroll
  for (int j = 0; j < 16; j++) { la[j] *= 5.0f; mx = fmaxf(mx, la[j]); }
  float sm = 0.f;
#pragma unroll
  for (int j = 0; j < 16; j++) sm += __expf(la[j] - mx);
  for (int off = 1; off < 4; off <<= 1) {   // combine 4 lanes of a row
    float mo = __shfl_xor(mx, off), so = __shfl_xor(sm, off);
    float mn = fmaxf(mx, mo);
    sm = sm * __expf(mx - mn) + so * __expf(mo - mn);
    mx = mn;
  }
  float rl = mx + __logf(sm);
  __shared__ float sla[64 * 65];
#pragma unroll
  for (int j = 0; j < 16; j++) sla[d * 65 + q * 16 + j] = la[j] - rl;
  __syncthreads();
  int e = t >> 2, jj = t & 3;     // col e, row segment jj*16..jj*16+15
  float lb[16]; float m2 = -3.0e38f;
#pragma unroll
  for (int i = 0; i < 16; i++) { lb[i] = sla[(jj * 16 + i) * 65 + e]; m2 = fmaxf(m2, lb[i]); }
  float s2 = 0.f;
#pragma unroll
  for (int i = 0; i < 16; i++) s2 += __expf(lb[i] - m2);
  for (int off = 1; off < 4; off <<= 1) {
    float mo = __shfl_xor(m2, off), so = __shfl_xor(s2, off);
    float mn = fmaxf(m2, mo);
    s2 = s2 * __expf(m2 - mn) + so * __expf(mo - mn);
    m2 = mn;
  }
  float cl = m2 + __logf(s2);
#pragma unroll
  for (int i = 0; i < 16; i++)
    Wt[tb * 4096 + e * 64 + jj * 16 + i] = f2bf(__expf(lb[i] - cl));  // Wt[t][o][i]=W[i][o]
}

// ------ K4 v2: x_local = x@W per n. LDS-free, barrier-free: each wave loads
// its MFMA fragments directly from global (x fp32 -> hi/lo bf16 in-register;
// Wt 16B contiguous, identical across waves -> L1 broadcast). xl fp16 [n][bk].
__global__ __launch_bounds__(256) void k_gemm1(const float* __restrict__ x,
                                               const u16* __restrict__ Wt,
                                               u16* __restrict__ xl) {
  int n = blockIdx.x, t = threadIdx.x, w = t >> 6, l = t & 63;
  int q = l >> 4, lr = l & 15;
  const float* xb = x + n * 64;
  const u16* wb = Wt + n * 4096;
  f32x4 acc[4][4] = {};
#pragma unroll
  for (int ks = 0; ks < 2; ks++) {
    bf16x8 bfr[4];
#pragma unroll
    for (int ni = 0; ni < 4; ni++)
      bfr[ni] = *(const bf16x8*)&wb[(ni * 16 + lr) * 64 + ks * 32 + q * 8];
#pragma unroll
    for (int mi = 0; mi < 4; mi++) {
      int b = w * 64 + mi * 16 + lr;
      const float* xr = xb + (size_t)b * 65536 + ks * 32 + q * 8;
      float4 v0 = *(const float4*)xr;
      float4 v1 = *(const float4*)(xr + 4);
      float vf[8] = {v0.x, v0.y, v0.z, v0.w, v1.x, v1.y, v1.z, v1.w};
      bf16x8 ah, al;
#pragma unroll
      for (int j = 0; j < 8; j++) {
        u16 h = f2bf(vf[j]);
        ah[j] = (short)h;
        al[j] = (short)f2bf(vf[j] - bf2f(h));
      }
#pragma unroll
      for (int ni = 0; ni < 4; ni++) {
        acc[mi][ni] = __builtin_amdgcn_mfma_f32_16x16x32_bf16(ah, bfr[ni], acc[mi][ni], 0, 0, 0);
        acc[mi][ni] = __builtin_amdgcn_mfma_f32_16x16x32_bf16(al, bfr[ni], acc[mi][ni], 0, 0, 0);
      }
    }
  }
#pragma unroll
  for (int mi = 0; mi < 4; mi++)
#pragma unroll
    for (int ni = 0; ni < 4; ni++) {
      int o = ni * 16 + lr;
#pragma unroll
      for (int reg = 0; reg < 4; reg++) {
        int b = w * 64 + mi * 16 + q * 4 + reg;
        xl[n * BKDIM + b * 64 + o] = f2h(acc[mi][ni][reg]);   // fp16 intermediate
      }
    }
}

// ------ K5a: LN stats partials over 128-row chunks -> Psum/Pssq/Pwg --------
__global__ __launch_bounds__(256) void k_stat(const u16* __restrict__ xl,
                                              const float* __restrict__ g2,
                                              float* __restrict__ Ps,
                                              float* __restrict__ Pq,
                                              float* __restrict__ Pw) {
  __shared__ float sS[16 * 132], sQ[16 * 132], sW[16 * 132];
  int cb = blockIdx.x, mc = blockIdx.y, t = threadIdx.x;
  int c0 = cb * 128;
  int rg = t >> 4, cs = (t & 15) * 8;
  float sum[8], ssq[8], wg[8];
#pragma unroll
  for (int j = 0; j < 8; j++) { sum[j] = 0.f; ssq[j] = 0.f; wg[j] = 0.f; }
  for (int it = 0; it < 8; it++) {
    int row = mc * 128 + it * 16 + rg;
    bf16x8 v = *(const bf16x8*)&xl[(size_t)row * BKDIM + c0 + cs];
    float gm = g2[row];
#pragma unroll
    for (int j = 0; j < 8; j++) {
      float f = h2f((u16)v[j]);
      sum[j] += f; ssq[j] += f * f; wg[j] += f * gm;
    }
  }
#pragma unroll
  for (int j = 0; j < 8; j++) {
    sS[rg * 132 + cs + j] = sum[j];
    sQ[rg * 132 + cs + j] = ssq[j];
    sW[rg * 132 + cs + j] = wg[j];
  }
  __syncthreads();
  if (t < 128) {
    float S = 0.f, Q = 0.f, W = 0.f;
    for (int k = 0; k < 16; k++) {
      S += sS[k * 132 + t]; Q += sQ[k * 132 + t]; W += sW[k * 132 + t];
    }
    Ps[mc * BKDIM + c0 + t] = S;
    Pq[mc * BKDIM + c0 + t] = Q;
    Pw[mc * BKDIM + c0 + t] = W;
  }
}

// ------ K5b: finalize mu/alpha/sON per bk ----------------------------------
__global__ __launch_bounds__(256) void k_fin(const float* __restrict__ Ps,
                                             const float* __restrict__ Pq,
                                             const float* __restrict__ Pw,
                                             const float* __restrict__ g2,
                                             const float* __restrict__ b2,
                                             float* __restrict__ mu,
                                             float* __restrict__ al,
                                             float* __restrict__ sON) {
  __shared__ float red[512];
  int t = threadIdx.x;
  float g = 0.f, b = 0.f;
#pragma unroll
  for (int k = 0; k < 4; k++) { g += g2[t * 4 + k]; b += b2[t * 4 + k]; }
  red[t] = g; red[256 + t] = b; __syncthreads();
  for (int s = 128; s > 0; s >>= 1) {
    if (t < s) { red[t] += red[t + s]; red[256 + t] += red[256 + t + s]; }
    __syncthreads();
  }
  float G = red[0], Bt = red[256];
  int bk = blockIdx.x * 256 + t;
  float S = 0.f, Q = 0.f, W = 0.f;
#pragma unroll
  for (int mc = 0; mc < 8; mc++) {
    S += Ps[mc * BKDIM + bk]; Q += Pq[mc * BKDIM + bk]; W += Pw[mc * BKDIM + bk];
  }
  float m_ = S * (1.0f / 1024.0f);
  float var = Q * (1.0f / 1024.0f) - m_ * m_;
  float a = rsqrtf(var + 1e-5f);
  mu[bk] = m_; al[bk] = a;
  sON[bk] = (a * (W - m_ * G) + Bt) * (1.0f / 1024.0f);
}

// ------ K5c: apply LN + transpose 128x128 tile -> xln[bk][m] bf16 ----------
// LDS col-major with XOR-on-m swizzle: element (col,m) at ldsT[col*128 + (m ^ ((col>>3)<<3))].
// Write side ~2-way bank aliasing (free), read side b128 2-way (free).
__global__ __launch_bounds__(256) void k_apply(const u16* __restrict__ xl,
                                               const float* __restrict__ g2,
                                               const float* __restrict__ b2,
                                               const float* __restrict__ mu,
                                               const float* __restrict__ al,
                                               u16* __restrict__ xln) {
  __shared__ __align__(16) u16 ldsT[128 * 128];  // 32KB
  int bkt = blockIdx.x, mc = blockIdx.y, t = threadIdx.x;
  int c0 = bkt * 128;
  int r = t >> 4, cs = t & 15;
  float mu8[8], al8[8];
#pragma unroll
  for (int j = 0; j < 8; j++) { mu8[j] = mu[c0 + cs * 8 + j]; al8[j] = al[c0 + cs * 8 + j]; }
  int key = cs << 3;
  for (int it = 0; it < 8; it++) {
    int m_ = it * 16 + r;
    int row = mc * 128 + m_;
    bf16x8 v = *(const bf16x8*)&xl[(size_t)row * BKDIM + c0 + cs * 8];
    float gm = g2[row], bt = b2[row];
    int pm = m_ ^ key;
#pragma unroll
    for (int j = 0; j < 8; j++) {
      float f = (h2f((u16)v[j]) - mu8[j]) * al8[j] * gm + bt;
      ldsT[(cs * 8 + j) * 128 + pm] = f2bf(f);
    }
  }
  __syncthreads();
  int ms = (t & 15) * 8;
  for (int it = 0; it < 8; it++) {
    int col = it * 16 + (t >> 4);
    int key2 = (col >> 3) << 3;
    bf16x8 o = *(const bf16x8*)&ldsT[col * 128 + (ms ^ key2)];
    *(bf16x8*)&xln[(size_t)(c0 + col) * NDIM + mc * 128 + ms] = o;
  }
}

// ------ K6: C^T[n2][bk] = sum_m Dt[n2][m]*xln[bk][m]; out = C^T + s/N (f32)
// async global_load_lds staging + XOR chunk swizzle (conflict-free reads).
__global__ __launch_bounds__(256) void k_gemm2(const u16* __restrict__ Dt,
                                               const u16* __restrict__ xln,
                                               const float* __restrict__ sON,
                                               float* __restrict__ out) {
  __shared__ __align__(16) u16 lA[128 * 64];  // [n2_local][m], swizzled
  __shared__ __align__(16) u16 lB[128 * 64];  // [bk_local][m], swizzled
  int bkt = blockIdx.x, n2t = blockIdx.y;
  int t = threadIdx.x, w = t >> 6, l = t & 63;
  int q = l >> 4, lr = l & 15;
  int rr = l >> 3;                 // row within 8-row group (0..7)
  int cc = (l & 7) ^ rr;           // logical chunk this lane fetches
  const u16* gA = Dt  + (size_t)(n2t * 128) * NDIM + cc * 8;
  const u16* gB = xln + (size_t)(bkt * 128) * NDIM + cc * 8;
  f32x4 acc[4][4] = {};
  for (int kt = 0; kt < 16; kt++) {
#pragma unroll
    for (int j = 0; j < 4; j++) {
      int ci = j * 4 + w;
      int row = ci * 8 + rr;
      async16(gA + (size_t)row * NDIM + kt * 64, &lA[ci * 512 + l * 8]);
      async16(gB + (size_t)row * NDIM + kt * 64, &lB[ci * 512 + l * 8]);
    }
    __syncthreads();   // drains vmcnt (global_load_lds) per barrier semantics
#pragma unroll
    for (int ks = 0; ks < 2; ks++) {
      int pc = ((ks * 4 + q) ^ (lr & 7)) * 8;   // physical chunk offset (halves)
      bf16x8 af[4], bfr[4];
#pragma unroll
      for (int mi = 0; mi < 4; mi++)
        af[mi] = *(const bf16x8*)&lA[((w >> 1) * 64 + mi * 16 + lr) * 64 + pc];
#pragma unroll
      for (int ni = 0; ni < 4; ni++)
        bfr[ni] = *(const bf16x8*)&lB[((w & 1) * 64 + ni * 16 + lr) * 64 + pc];
#pragma unroll
      for (int mi = 0; mi < 4; mi++)
#pragma unroll
        for (int ni = 0; ni < 4; ni++)
          acc[mi][ni] = __builtin_amdgcn_mfma_f32_16x16x32_bf16(af[mi], bfr[ni], acc[mi][ni], 0, 0, 0);
    }
    __syncthreads();   // tile consumed before next iter's DMA overwrites
  }
#pragma unroll
  for (int ni = 0; ni < 4; ni++) {
    int bk = bkt * 128 + (w & 1) * 64 + ni * 16 + lr;
    float sN = sON[bk];
    int b = bk >> 6, o = bk & 63;
#pragma unroll
    for (int mi = 0; mi < 4; mi++)
#pragma unroll
      for (int reg = 0; reg < 4; reg++) {
        int n2 = n2t * 128 + (w >> 1) * 64 + mi * 16 + q * 4 + reg;
        out[(size_t)b * 65536 + n2 * 64 + o] = acc[mi][ni][reg] + sN;   // fp32 store
      }
  }
}

extern "C" void kernel_launch(void* const* d_in, const int* in_sizes, int n_in,
                              void* d_out, int out_size, void* d_ws, size_t ws_size,
                              hipStream_t stream) {
  const float* x    = (const float*)d_in[0];
  const float* Alog = (const float*)d_in[1];
  const float* W1   = (const float*)d_in[2];
  const float* WV   = (const float*)d_in[3];
  const float* g2   = (const float*)d_in[4];
  const float* b2   = (const float*)d_in[5];
  float* out = (float*)d_out;                       // fp32 output, 64 MiB
  char* ws = (char*)d_ws;

  u16*   xln = (u16*)(ws);                          // 32 MiB: [16384][1024] bf16
  u16*   Wt  = (u16*)(ws + 33554432ull);            //  8 MiB: [1024][4096] bf16
  u16*   Dt  = (u16*)(ws + 41943040ull);            //  2 MiB: [1024][1024] bf16
  float* r   = (float*)(ws + 44040192ull);          //  4 KiB
  float* sON = (float*)(ws + 44044288ull);          // 64 KiB (read by k_gemm2 -> must be in ws)
  // Scratch in d_out (dead before k_gemm2 overwrites all of d_out):
  //   upper 32 MiB: xl fp16 [1024][16384]
  //   lower region: LN partials + mu/al (all consumed by k_apply before k_gemm2)
  u16*   xl  = (u16*)((char*)d_out + 33554432ull);  // 32 MiB
  float* Ps  = (float*)((char*)d_out);              // 512 KiB: [8][16384]
  float* Pq  = (float*)((char*)d_out + 524288ull);  // 512 KiB
  float* Pw  = (float*)((char*)d_out + 1048576ull); // 512 KiB
  float* mu  = (float*)((char*)d_out + 1572864ull); //  64 KiB
  float* al  = (float*)((char*)d_out + 1638400ull); //  64 KiB

  k_row_lse<<<dim3(1024), dim3(256), 0, stream>>>(Alog, r);
  k_col_dt<<<dim3(1024), dim3(256), 0, stream>>>(Alog, r, Dt);
  k_w<<<dim3(1024), dim3(256), 0, stream>>>(W1, WV, Wt);
  k_gemm1<<<dim3(1024), dim3(256), 0, stream>>>(x, Wt, xl);
  k_stat<<<dim3(128, 8), dim3(256), 0, stream>>>(xl, g2, Ps, Pq, Pw);
  k_fin<<<dim3(64), dim3(256), 0, stream>>>(Ps, Pq, Pw, g2, b2, mu, al, sON);
  k_apply<<<dim3(128, 8), dim3(256), 0, stream>>>(xl, g2, b2, mu, al, xln);
  k_gemm2<<<dim3(128, 8), dim3(256), 0, stream>>>(Dt, xln, sON, out);
}